// Round 2
// baseline (138.451 us; speedup 1.0000x reference)
//
#include <hip/hip_runtime.h>

#define Bn 16
#define Cn 64
#define Hn 128
#define Wn 128
#define HWn (Hn * Wn)

typedef __attribute__((ext_vector_type(8)))  short  short8;    // 8 bf16
typedef __attribute__((ext_vector_type(16))) float  floatx16;  // 32x32 C/D
typedef __attribute__((ext_vector_type(4)))  float  floatx4;
using int32x4 = int __attribute__((ext_vector_type(4)));

__device__ floatx4
llvm_amdgcn_raw_buffer_load_v4f32(int32x4 srsrc, int voffset, int soffset,
                                  int aux) __asm("llvm.amdgcn.raw.buffer.load.v4f32");

__device__ __forceinline__ int32x4 make_rsrc(const void* p, int bytes) {
    int32x4 r;
    r.x = (int)(unsigned)(uintptr_t)p;
    r.y = (int)((uintptr_t)p >> 32);   // stride=0
    r.z = bytes;                        // num_records
    r.w = 0x00020000;                   // raw dword SRD
    return r;
}

__device__ __forceinline__ unsigned short f2bf(float f) {  // RNE f32->bf16
    unsigned u = __float_as_uint(f);
    u += 0x7fffu + ((u >> 16) & 1u);
    return (unsigned short)(u >> 16);
}
__device__ __forceinline__ float lrelu(float v) { return v >= 0.f ? v : 0.1f * v; }

// Barrier that does NOT drain vmcnt: LDS-only wait + raw s_barrier.
// (hipcc's __syncthreads emits s_waitcnt vmcnt(0) before s_barrier, which
// force-drains the register-prefetch pipeline — the R7 neutral result.)
// Our cross-wave data is ONLY the dwB LDS buffer, so lgkmcnt(0) suffices;
// x/k/a prefetch results are wave-private registers.
#define SYNC_LDS() asm volatile("s_waitcnt lgkmcnt(0)\n\ts_barrier" ::: "memory")

// ---------------------------------------------------------------------------
// Kernel-gen (R5 proven structure, unchanged). Outputs:
//   kernP[b][c][12]  fp32, taps 0..8 at [0..8], pad [9..11] (16B-aligned rows)
//   WcBF [o][c]      bf16 RNE (row-major, A-operand friendly)
// ---------------------------------------------------------------------------
__global__ __launch_bounds__(192)
void gen_kern6(const float* __restrict__ d,
               const float* __restrict__ Wk1,
               const float* __restrict__ Wk2,
               const float* __restrict__ Wc,
               float* __restrict__ kernP,            // ws: [16][64][12]
               unsigned short* __restrict__ WcBF) {  // ws: [64][64] bf16
    const int b = blockIdx.x;   // 16
    const int r = blockIdx.y;   // 3
    const int t = threadIdx.x;  // 192
    __shared__ float hid_s[64];

    if (t < 64) {
        const float4* __restrict__ w4 = (const float4*)(Wk1 + (size_t)t * 64);
        const float*  __restrict__ db = d + b * 64;
        float s0 = 0.f, s1 = 0.f, s2 = 0.f, s3 = 0.f;
        #pragma unroll
        for (int j = 0; j < 16; ++j) {
            const float4 wv = w4[j];
            s0 += db[4 * j + 0] * wv.x;
            s1 += db[4 * j + 1] * wv.y;
            s2 += db[4 * j + 2] * wv.z;
            s3 += db[4 * j + 3] * wv.w;
        }
        hid_s[t] = lrelu((s0 + s1) + (s2 + s3));
    }
    __syncthreads();

    {
        const int o = r * 192 + t;                   // 576 = 3*192
        const float4* __restrict__ w4 = (const float4*)(Wk2 + (size_t)o * 64);
        const float4* __restrict__ h4 = (const float4*)hid_s;
        float s0 = 0.f, s1 = 0.f, s2 = 0.f, s3 = 0.f;
        #pragma unroll
        for (int j = 0; j < 16; ++j) {
            const float4 wv = w4[j];
            const float4 hv = h4[j];
            s0 += hv.x * wv.x;
            s1 += hv.y * wv.y;
            s2 += hv.z * wv.z;
            s3 += hv.w * wv.w;
        }
        const int c = o / 9, tap = o - c * 9;
        kernP[b * 768 + c * 12 + tap] = (s0 + s1) + (s2 + s3);
    }

    if (b == 0 && r == 0) {
        for (int idx = t; idx < 4096; idx += 192)
            WcBF[idx] = f2bf(Wc[idx]);
    }
}

// ---------------------------------------------------------------------------
// Main fused conv, R8: R7 data path (bit-identical numerics) + real pipeline.
//   * SYNC_LDS barriers (lgkmcnt-only) keep register prefetch alive across
//     group boundaries (T4 counted-vmcnt mechanism).
//   * Issue-order discipline: per iter g, the single MFMA vmcnt wait (on the
//     a-frag issued LAST iter) drains exactly the loads this iter consumes
//     and leaves x(g+2) / a(g+1) / k(g+2) — issued at this iter's top — in
//     flight. No wait ever drains the pipe to vmcnt(0) in the loop.
//   * Bias applied at store time via float4 loads (prologue stays clean).
// ---------------------------------------------------------------------------
struct XK { floatx4 x[3][2]; };                     // 3 rows x 8 px
struct KF { floatx4 k0, k1; float k8; };            // taps 0..3, 4..7, 8

__device__ __forceinline__ void issue_x(XK& v, int32x4 rs, int c,
                                        const int* rofsB, int px0) {
    #pragma unroll
    for (int r = 0; r < 3; ++r) {
        const int vo = (c << 16) + rofsB[r] + px0 * 4;
        v.x[r][0] = llvm_amdgcn_raw_buffer_load_v4f32(rs, vo, 0, 0);
        v.x[r][1] = llvm_amdgcn_raw_buffer_load_v4f32(rs, vo + 16, 0, 0);
    }
}

__device__ __forceinline__ void issue_k(KF& kf, const float* kp, int c) {
    const floatx4* k4 = (const floatx4*)(kp + c * 12);
    kf.k0 = k4[0];
    kf.k1 = k4[1];
    kf.k8 = ((const float*)k4)[8];
}

__device__ __forceinline__ short8 compute_dw(const XK& v, const KF& kf,
                                             int lane, int tm) {
    float t0[8], t1[8], t2[8];                // column sums per dx
    #pragma unroll
    for (int i = 0; i < 8; ++i) {
        const float xr0 = (i < 4) ? v.x[0][0][i] : v.x[0][1][i - 4];
        const float xr1 = (i < 4) ? v.x[1][0][i] : v.x[1][1][i - 4];
        const float xr2 = (i < 4) ? v.x[2][0][i] : v.x[2][1][i - 4];
        t0[i] = kf.k0.x * xr0 + kf.k0.w * xr1 + kf.k1.z * xr2; // taps 0,3,6
        t1[i] = kf.k0.y * xr0 + kf.k1.x * xr1 + kf.k1.w * xr2; // taps 1,4,7
        t2[i] = kf.k0.z * xr0 + kf.k1.y * xr1 + kf.k8   * xr2; // taps 2,5,8
    }
    // halo from px-octet neighbors (same wave: tm>0 => lane-1 same wave)
    float t0m = __shfl(t0[7], lane - 1, 64);  // left  neighbor's t0[px0-1]
    float t2p = __shfl(t2[0], lane + 1, 64);  // right neighbor's t2[px0+8]
    if (tm == 0)  t0m = 0.f;                  // px = -1  border
    if (tm == 15) t2p = 0.f;                  // px = 128 border

    float dw[8];
    dw[0] = t0m + t1[0] + t2[1];
    #pragma unroll
    for (int i = 1; i < 7; ++i) dw[i] = t0[i - 1] + t1[i] + t2[i + 1];
    dw[7] = t0[6] + t1[7] + t2p;

    short8 w8;
    #pragma unroll
    for (int i = 0; i < 8; ++i) w8[i] = (short)f2bf(lrelu(dw[i]));
    return w8;
}

__global__ __launch_bounds__(256)
void da_mfma4(const float* __restrict__ x,
              const float* __restrict__ kernP,
              const unsigned short* __restrict__ WcBF,
              const float* __restrict__ bc,
              float* __restrict__ out) {
    const int t    = threadIdx.x;
    const int lane = t & 63;
    const int wv   = t >> 6;            // wave 0..3 -> px tile
    const int col  = lane & 31;         // px within tile / A-B n,m index
    const int kh   = lane >> 5;         // k-half (8 ch)
    const int bx   = blockIdx.x;        // 128
    const int h    = ((bx & 7) << 4) | (bx >> 3);   // XCD-band swizzle
    const int b    = blockIdx.y;        // 16
    const int px   = wv * 32 + col;

    // staging mapping
    const int sch = t >> 4;             // 0..15 (channel within group)
    const int tm  = t & 15;
    const int px0 = tm * 8;             // 8-px octet

    // dw exchange buffers: [buf][ch][px] bf16, px XOR-32-swizzled for ch&8
    __shared__ unsigned short dwB[2][2048];   // 8 KB total

    // vertical row byte-offsets; border -> OOB sentinel (loads return 0)
    int rofsB[3];
    #pragma unroll
    for (int i = 0; i < 3; ++i) {
        const int hh = h + i - 1;
        rofsB[i] = (hh >= 0 && hh < Hn) ? hh * (Wn * 4) : 0x10000000;
    }

    const int32x4 rs = make_rsrc(x + (size_t)b * Cn * HWn, Cn * HWn * 4);
    const float* __restrict__ kp = kernP + b * 768;

    floatx16 acc[2];
    #pragma unroll
    for (int m = 0; m < 2; ++m)
        #pragma unroll
        for (int r = 0; r < 16; ++r)
            acc[m][r] = 0.f;

    // ---- prologue (issue order matters: consumers must be OLDER than
    //      prefetches so per-use vmcnt waits never drain the pipe) ----
    XK X[4]; KF Kf[4]; short8 a0[4], a1[4];
    a0[0] = *(const short8*)(WcBF + (0 * 32 + col) * 64 + 0 * 16 + kh * 8);
    a1[0] = *(const short8*)(WcBF + (1 * 32 + col) * 64 + 0 * 16 + kh * 8);
    issue_k(Kf[0], kp, sch);
    issue_k(Kf[1], kp, 16 + sch);
    issue_x(X[0], rs, sch, rofsB, px0);
    issue_x(X[1], rs, 16 + sch, rofsB, px0);
    {
        const short8 w8 = compute_dw(X[0], Kf[0], lane, tm);  // waits X0 only
        *(short8*)&dwB[0][sch * 128 + (px0 ^ ((sch & 8) << 2))] = w8;
    }
    SYNC_LDS();

    // ---- pipelined group loop: x depth-2, a/k depth-1, no vmcnt(0) ----
    #pragma unroll
    for (int g = 0; g < 4; ++g) {
        if (g < 2) issue_x(X[g + 2], rs, (g + 2) * 16 + sch, rofsB, px0);
        if (g < 3) {
            a0[g + 1] = *(const short8*)(WcBF + (0 * 32 + col) * 64 + (g + 1) * 16 + kh * 8);
            a1[g + 1] = *(const short8*)(WcBF + (1 * 32 + col) * 64 + (g + 1) * 16 + kh * 8);
        }
        if (g < 2) issue_k(Kf[g + 2], kp, (g + 2) * 16 + sch);

        // B-frag read: 8x ds_read_u16, banks balanced via XOR-32 swizzle
        short8 bfr;
        #pragma unroll
        for (int j = 0; j < 8; ++j) {
            const int cl = kh * 8 + j;
            bfr[j] = (short)dwB[g & 1][cl * 128 + (px ^ ((cl & 8) << 2))];
        }
        acc[0] = __builtin_amdgcn_mfma_f32_32x32x16_bf16(a0[g], bfr, acc[0], 0, 0, 0);
        acc[1] = __builtin_amdgcn_mfma_f32_32x32x16_bf16(a1[g], bfr, acc[1], 0, 0, 0);

        if (g < 3) {
            const short8 w8 = compute_dw(X[g + 1], Kf[g + 1], lane, tm);
            *(short8*)&dwB[(g + 1) & 1][sch * 128 + (px0 ^ ((sch & 8) << 2))] = w8;
            SYNC_LDS();
        }
    }

    // ---- STORE: full 128B lines; bias added here (float4 bc loads) ----
    float* __restrict__ ob = out + (size_t)b * Cn * HWn + h * Wn + px;
    #pragma unroll
    for (int m = 0; m < 2; ++m)
        #pragma unroll
        for (int q = 0; q < 4; ++q) {
            const float4 bv = *(const float4*)&bc[m * 32 + q * 8 + 4 * kh];
            #pragma unroll
            for (int j = 0; j < 4; ++j) {
                const int o = m * 32 + q * 8 + 4 * kh + j;
                ob[(size_t)o * HWn] = acc[m][q * 4 + j] + ((const float*)&bv)[j];
            }
        }
}

// ---------------------------------------------------------------------------
extern "C" void kernel_launch(void* const* d_in, const int* in_sizes, int n_in,
                              void* d_out, int out_size, void* d_ws, size_t ws_size,
                              hipStream_t stream) {
    const float* x   = (const float*)d_in[0];
    const float* d   = (const float*)d_in[1];
    const float* Wk1 = (const float*)d_in[2];
    const float* Wk2 = (const float*)d_in[3];
    const float* Wc  = (const float*)d_in[4];
    const float* bc  = (const float*)d_in[5];
    float* out = (float*)d_out;
    float*          kernP = (float*)d_ws;                         // 16*768 fp32
    unsigned short* WcBF  = (unsigned short*)((float*)d_ws + Bn * 768); // 64*64 bf16

    gen_kern6<<<dim3(Bn, 3), dim3(192), 0, stream>>>(d, Wk1, Wk2, Wc, kernP, WcBF);
    da_mfma4<<<dim3(Hn, Bn), dim3(256), 0, stream>>>(x, kernP, WcBF, bc, out);
}

// Round 3
// 137.699 us; speedup vs baseline: 1.0055x; 1.0055x over previous
//
#include <hip/hip_runtime.h>

#define Bn 16
#define Cn 64
#define Hn 128
#define Wn 128
#define HWn (Hn * Wn)

typedef __attribute__((ext_vector_type(8)))  short  short8;    // 8 bf16
typedef __attribute__((ext_vector_type(16))) float  floatx16;  // 32x32 C/D
typedef __attribute__((ext_vector_type(4)))  float  floatx4;
using int32x4 = int __attribute__((ext_vector_type(4)));

__device__ floatx4
llvm_amdgcn_raw_buffer_load_v4f32(int32x4 srsrc, int voffset, int soffset,
                                  int aux) __asm("llvm.amdgcn.raw.buffer.load.v4f32");

__device__ __forceinline__ int32x4 make_rsrc(const void* p, int bytes) {
    int32x4 r;
    r.x = (int)(unsigned)(uintptr_t)p;
    r.y = (int)((uintptr_t)p >> 32);   // stride=0
    r.z = bytes;                        // num_records
    r.w = 0x00020000;                   // raw dword SRD
    return r;
}

__device__ __forceinline__ unsigned short f2bf(float f) {  // RNE f32->bf16
    unsigned u = __float_as_uint(f);
    u += 0x7fffu + ((u >> 16) & 1u);
    return (unsigned short)(u >> 16);
}
__device__ __forceinline__ float lrelu(float v) { return v >= 0.f ? v : 0.1f * v; }

// Barrier that does NOT drain vmcnt: LDS-only wait + raw s_barrier.
// Cross-wave data is ONLY the dwB LDS buffer, so lgkmcnt(0) suffices;
// x/k/a prefetch results are wave-private registers and may stay in flight.
#define SYNC_LDS() asm volatile("s_waitcnt lgkmcnt(0)\n\ts_barrier" ::: "memory")

// ---------------------------------------------------------------------------
// Kernel-gen. Outputs:
//   kernP[b][c][12]  fp32, taps 0..8 at [0..8], pad [9..11] (16B-aligned rows)
//   WcT  [m][g][lane][8] bf16 — A-frag table PRE-TRANSPOSED so a wave's
//     64 lanes read 1 KB CONTIGUOUS per fragment (the old [o][c] layout made
//     each a-load a 64-cache-line gather: 128 B/lane stride).
//     Element: WcT[((m*4+g)*64 + lane)*8 + j] = Wc[(m*32+col)*64 + g*16+kh*8+j],
//     lane = kh*32+col.
// ---------------------------------------------------------------------------
__global__ __launch_bounds__(192)
void gen_kern7(const float* __restrict__ d,
               const float* __restrict__ Wk1,
               const float* __restrict__ Wk2,
               const float* __restrict__ Wc,
               float* __restrict__ kernP,            // ws: [16][64][12]
               unsigned short* __restrict__ WcT) {   // ws: 4096 bf16 (8 KB)
    const int b = blockIdx.x;   // 16
    const int r = blockIdx.y;   // 3
    const int t = threadIdx.x;  // 192
    __shared__ float hid_s[64];

    if (t < 64) {
        const float4* __restrict__ w4 = (const float4*)(Wk1 + (size_t)t * 64);
        const float*  __restrict__ db = d + b * 64;
        float s0 = 0.f, s1 = 0.f, s2 = 0.f, s3 = 0.f;
        #pragma unroll
        for (int j = 0; j < 16; ++j) {
            const float4 wv = w4[j];
            s0 += db[4 * j + 0] * wv.x;
            s1 += db[4 * j + 1] * wv.y;
            s2 += db[4 * j + 2] * wv.z;
            s3 += db[4 * j + 3] * wv.w;
        }
        hid_s[t] = lrelu((s0 + s1) + (s2 + s3));
    }
    __syncthreads();

    {
        const int o = r * 192 + t;                   // 576 = 3*192
        const float4* __restrict__ w4 = (const float4*)(Wk2 + (size_t)o * 64);
        const float4* __restrict__ h4 = (const float4*)hid_s;
        float s0 = 0.f, s1 = 0.f, s2 = 0.f, s3 = 0.f;
        #pragma unroll
        for (int j = 0; j < 16; ++j) {
            const float4 wv = w4[j];
            const float4 hv = h4[j];
            s0 += hv.x * wv.x;
            s1 += hv.y * wv.y;
            s2 += hv.z * wv.z;
            s3 += hv.w * wv.w;
        }
        const int c = o / 9, tap = o - c * 9;
        kernP[b * 768 + c * 12 + tap] = (s0 + s1) + (s2 + s3);
    }

    if (b == 0 && r == 0) {
        for (int idx = t; idx < 4096; idx += 192) {
            const int j    = idx & 7;
            const int lane = (idx >> 3) & 63;
            const int g    = (idx >> 9) & 3;
            const int m    = idx >> 11;
            const int col  = lane & 31, kh = lane >> 5;
            const int o    = m * 32 + col;
            const int c    = g * 16 + kh * 8 + j;
            WcT[idx] = f2bf(Wc[o * 64 + c]);
        }
    }
}

// ---------------------------------------------------------------------------
// Main fused conv, R9: R8 pipeline + the registers to actually hold it.
//   * __launch_bounds__(256, 4): 128-VGPR cap (was 64 via default max-occ
//     target -> compiler sank the X prefetch next to its use, serializing
//     every phase on L2/L3 latency; VGPR_Count=60 was the smoking gun).
//     16 waves/CU + real depth-2 prefetch instead of 32 waves of convoys.
//   * A-frags from transposed WcT: coalesced 1 KB/instr, L1-broadcast.
//   * SYNC_LDS barriers (lgkmcnt-only) keep vmcnt prefetch alive across
//     group boundaries; issue order keeps consumers older than prefetches.
// ---------------------------------------------------------------------------
struct XK { floatx4 x[3][2]; };                     // 3 rows x 8 px
struct KF { floatx4 k0, k1; float k8; };            // taps 0..3, 4..7, 8

__device__ __forceinline__ void issue_x(XK& v, int32x4 rs, int c,
                                        const int* rofsB, int px0) {
    #pragma unroll
    for (int r = 0; r < 3; ++r) {
        const int vo = (c << 16) + rofsB[r] + px0 * 4;
        v.x[r][0] = llvm_amdgcn_raw_buffer_load_v4f32(rs, vo, 0, 0);
        v.x[r][1] = llvm_amdgcn_raw_buffer_load_v4f32(rs, vo + 16, 0, 0);
    }
}

__device__ __forceinline__ void issue_k(KF& kf, const float* kp, int c) {
    const floatx4* k4 = (const floatx4*)(kp + c * 12);
    kf.k0 = k4[0];
    kf.k1 = k4[1];
    kf.k8 = ((const float*)k4)[8];
}

__device__ __forceinline__ short8 compute_dw(const XK& v, const KF& kf,
                                             int lane, int tm) {
    float t0[8], t1[8], t2[8];                // column sums per dx
    #pragma unroll
    for (int i = 0; i < 8; ++i) {
        const float xr0 = (i < 4) ? v.x[0][0][i] : v.x[0][1][i - 4];
        const float xr1 = (i < 4) ? v.x[1][0][i] : v.x[1][1][i - 4];
        const float xr2 = (i < 4) ? v.x[2][0][i] : v.x[2][1][i - 4];
        t0[i] = kf.k0.x * xr0 + kf.k0.w * xr1 + kf.k1.z * xr2; // taps 0,3,6
        t1[i] = kf.k0.y * xr0 + kf.k1.x * xr1 + kf.k1.w * xr2; // taps 1,4,7
        t2[i] = kf.k0.z * xr0 + kf.k1.y * xr1 + kf.k8   * xr2; // taps 2,5,8
    }
    // halo from px-octet neighbors (same wave: tm>0 => lane-1 same wave)
    float t0m = __shfl(t0[7], lane - 1, 64);  // left  neighbor's t0[px0-1]
    float t2p = __shfl(t2[0], lane + 1, 64);  // right neighbor's t2[px0+8]
    if (tm == 0)  t0m = 0.f;                  // px = -1  border
    if (tm == 15) t2p = 0.f;                  // px = 128 border

    float dw[8];
    dw[0] = t0m + t1[0] + t2[1];
    #pragma unroll
    for (int i = 1; i < 7; ++i) dw[i] = t0[i - 1] + t1[i] + t2[i + 1];
    dw[7] = t0[6] + t1[7] + t2p;

    short8 w8;
    #pragma unroll
    for (int i = 0; i < 8; ++i) w8[i] = (short)f2bf(lrelu(dw[i]));
    return w8;
}

__global__ __launch_bounds__(256, 4)
void da_mfma5(const float* __restrict__ x,
              const float* __restrict__ kernP,
              const unsigned short* __restrict__ WcT,
              const float* __restrict__ bc,
              float* __restrict__ out) {
    const int t    = threadIdx.x;
    const int lane = t & 63;
    const int wv   = t >> 6;            // wave 0..3 -> px tile
    const int col  = lane & 31;         // px within tile / A-B n,m index
    const int kh   = lane >> 5;         // k-half (8 ch)
    const int bx   = blockIdx.x;        // 128
    const int h    = ((bx & 7) << 4) | (bx >> 3);   // XCD-band swizzle
    const int b    = blockIdx.y;        // 16
    const int px   = wv * 32 + col;

    // staging mapping
    const int sch = t >> 4;             // 0..15 (channel within group)
    const int tm  = t & 15;
    const int px0 = tm * 8;             // 8-px octet

    // dw exchange buffers: [buf][ch][px] bf16, px XOR-32-swizzled for ch&8
    __shared__ unsigned short dwB[2][2048];   // 8 KB total

    // vertical row byte-offsets; border -> OOB sentinel (loads return 0)
    int rofsB[3];
    #pragma unroll
    for (int i = 0; i < 3; ++i) {
        const int hh = h + i - 1;
        rofsB[i] = (hh >= 0 && hh < Hn) ? hh * (Wn * 4) : 0x10000000;
    }

    const int32x4 rs = make_rsrc(x + (size_t)b * Cn * HWn, Cn * HWn * 4);
    const float* __restrict__ kp = kernP + b * 768;

    floatx16 acc[2];
    #pragma unroll
    for (int m = 0; m < 2; ++m)
        #pragma unroll
        for (int r = 0; r < 16; ++r)
            acc[m][r] = 0.f;

    // ---- prologue (issue order: consumers OLDER than prefetches) ----
    XK X[4]; KF Kf[4]; short8 a0[4], a1[4];
    a0[0] = *(const short8*)(WcT + ((0 * 4 + 0) * 64 + lane) * 8);
    a1[0] = *(const short8*)(WcT + ((1 * 4 + 0) * 64 + lane) * 8);
    issue_k(Kf[0], kp, sch);
    issue_k(Kf[1], kp, 16 + sch);
    issue_x(X[0], rs, sch, rofsB, px0);
    issue_x(X[1], rs, 16 + sch, rofsB, px0);
    {
        const short8 w8 = compute_dw(X[0], Kf[0], lane, tm);  // waits X0 only
        *(short8*)&dwB[0][sch * 128 + (px0 ^ ((sch & 8) << 2))] = w8;
    }
    SYNC_LDS();

    // ---- pipelined group loop: x depth-2, a/k depth-1, no vmcnt(0) ----
    #pragma unroll
    for (int g = 0; g < 4; ++g) {
        if (g < 2) issue_x(X[g + 2], rs, (g + 2) * 16 + sch, rofsB, px0);
        if (g < 3) {
            a0[g + 1] = *(const short8*)(WcT + ((0 * 4 + g + 1) * 64 + lane) * 8);
            a1[g + 1] = *(const short8*)(WcT + ((1 * 4 + g + 1) * 64 + lane) * 8);
        }
        if (g < 2) issue_k(Kf[g + 2], kp, (g + 2) * 16 + sch);

        // B-frag read: 8x ds_read_u16, banks balanced via XOR-32 swizzle
        short8 bfr;
        #pragma unroll
        for (int j = 0; j < 8; ++j) {
            const int cl = kh * 8 + j;
            bfr[j] = (short)dwB[g & 1][cl * 128 + (px ^ ((cl & 8) << 2))];
        }
        acc[0] = __builtin_amdgcn_mfma_f32_32x32x16_bf16(a0[g], bfr, acc[0], 0, 0, 0);
        acc[1] = __builtin_amdgcn_mfma_f32_32x32x16_bf16(a1[g], bfr, acc[1], 0, 0, 0);

        if (g < 3) {
            const short8 w8 = compute_dw(X[g + 1], Kf[g + 1], lane, tm);
            *(short8*)&dwB[(g + 1) & 1][sch * 128 + (px0 ^ ((sch & 8) << 2))] = w8;
            SYNC_LDS();
        }
    }

    // ---- STORE: full 128B lines; bias added here (float4 bc loads) ----
    float* __restrict__ ob = out + (size_t)b * Cn * HWn + h * Wn + px;
    #pragma unroll
    for (int m = 0; m < 2; ++m)
        #pragma unroll
        for (int q = 0; q < 4; ++q) {
            const float4 bv = *(const float4*)&bc[m * 32 + q * 8 + 4 * kh];
            #pragma unroll
            for (int j = 0; j < 4; ++j) {
                const int o = m * 32 + q * 8 + 4 * kh + j;
                ob[(size_t)o * HWn] = acc[m][q * 4 + j] + ((const float*)&bv)[j];
            }
        }
}

// ---------------------------------------------------------------------------
extern "C" void kernel_launch(void* const* d_in, const int* in_sizes, int n_in,
                              void* d_out, int out_size, void* d_ws, size_t ws_size,
                              hipStream_t stream) {
    const float* x   = (const float*)d_in[0];
    const float* d   = (const float*)d_in[1];
    const float* Wk1 = (const float*)d_in[2];
    const float* Wk2 = (const float*)d_in[3];
    const float* Wc  = (const float*)d_in[4];
    const float* bc  = (const float*)d_in[5];
    float* out = (float*)d_out;
    float*          kernP = (float*)d_ws;                         // 16*768 fp32
    unsigned short* WcT   = (unsigned short*)((float*)d_ws + Bn * 768); // 4096 bf16

    gen_kern7<<<dim3(Bn, 3), dim3(192), 0, stream>>>(d, Wk1, Wk2, Wc, kernP, WcT);
    da_mfma5<<<dim3(Hn, Bn), dim3(256), 0, stream>>>(x, kernP, WcT, bc, out);
}